// Round 29
// baseline (57.986 us; speedup 1.0000x reference)
//
#include <hip/hip_runtime.h>
#include <hip/hip_bf16.h>

typedef unsigned short u16;
typedef __attribute__((ext_vector_type(8))) __bf16 bf16x8;
typedef __attribute__((ext_vector_type(4))) float f32x4;

#define B_ 4
#define T_ 2048
#define C_ 1024
#define H_ 64
#define NSEG 8
#define GRID 256

__device__ __forceinline__ u16 f2bf(float f) {
    union { __hip_bfloat16 h; u16 u; } cv;
    cv.h = __float2bfloat16(f);
    return cv.u;
}

__device__ __forceinline__ bf16x8 cvt8r(float4 f0, float4 f1) {
    union { u16 h[8]; bf16x8 v; } ua;
    ua.h[0] = f2bf(f0.x); ua.h[1] = f2bf(f0.y);
    ua.h[2] = f2bf(f0.z); ua.h[3] = f2bf(f0.w);
    ua.h[4] = f2bf(f1.x); ua.h[5] = f2bf(f1.y);
    ua.h[6] = f2bf(f1.z); ua.h[7] = f2bf(f1.w);
    return ua.v;
}

// async global -> LDS, 16B per lane; LDS dest = uniform base + lane*16
__device__ __forceinline__ void gll16(const void* g, void* l) {
    __builtin_amdgcn_global_load_lds(
        (const __attribute__((address_space(1))) void*)g,
        (__attribute__((address_space(3))) void*)l, 16, 0, 0);
}

// ---------------- Kernel 0: W fp32 -> FRAGMENT-PACKED bf16 + bar reset ----
__global__ __launch_bounds__(256) void wpack(
    const float* __restrict__ wq, const float* __restrict__ wk,
    const float* __restrict__ wv, u16* __restrict__ wP,
    unsigned* __restrict__ bar)
{
    if (blockIdx.x == 0 && threadIdx.x == 0) bar[0] = 0;   // re-arm grid barrier
    int u    = blockIdx.x * 256 + threadIdx.x;   // 0..24575
    int ln   = u & 63;
    int frag = u >> 6;                           // 0..383
    int ksg  = frag & 31;
    int j16  = frag >> 5;                        // 0..11
    int n    = j16 * 16 + (ln & 15);
    int kb   = ksg * 32 + (ln >> 4) * 8;
    const float* src = (n < 64) ? (wq + (size_t)n * C_)
                     : (n < 128) ? (wk + (size_t)(n - 64) * C_)
                                 : (wv + (size_t)(n - 128) * C_);
    float4 f0 = *(const float4*)(src + kb);
    float4 f1 = *(const float4*)(src + kb + 4);
    *(bf16x8*)(wP + (size_t)u * 8) = cvt8r(f0, f1);
}

// ---------------- Fused: qkv (R27) -> grid barrier -> attn (R27) x2 -------
__global__ __launch_bounds__(512) void fused(
    const float* __restrict__ x, const u16* __restrict__ wP,
    u16* __restrict__ qP, u16* __restrict__ kP, u16* __restrict__ vP,
    float* __restrict__ out, unsigned* __restrict__ bar)
{
    __shared__ __align__(16) char shm[34816];

    const int tid = threadIdx.x;
    const int ln  = tid & 63;
    const int w   = tid >> 6;                    // 0..7
    const int lr  = ln & 15;
    const int g   = ln >> 4;
    const int lk  = g * 8;

    // ================= phase 1: QKV projection (R27) ======================
    {
        char* smem = shm;                        // 32KB of the 34.8KB
        const int m0 = blockIdx.x * 32;
        const int ms = w >> 2;
        const int nh = w & 3;

        f32x4 acc[3] = {};

        const int xrow = w * 4 + (ln >> 4);
        const int xc   = (ln & 15) ^ (xrow & 7);

#define STAGE(BUF, KC)                                                     \
    gll16(x + (size_t)(m0 + xrow) * C_ + (KC) * 64 + xc * 4,               \
          smem + (BUF) * 8192 + w * 1024)

        STAGE(0, 0);
        STAGE(1, 1);
        STAGE(2, 2);

        const int ra  = ms * 16 + lr;
        const int rsw = ra & 7;
        const u16* wbase = wP + (size_t)(nh * 3) * 32 * 64 * 8;

        #pragma unroll
        for (int kc = 0; kc < 16; ++kc) {
            if (kc == 0)       asm volatile("s_waitcnt vmcnt(2)"  ::: "memory");
            else if (kc == 1)  asm volatile("s_waitcnt vmcnt(8)"  ::: "memory");
            else if (kc <= 13) asm volatile("s_waitcnt vmcnt(14)" ::: "memory");
            else if (kc == 14) asm volatile("s_waitcnt vmcnt(13)" ::: "memory");
            else               asm volatile("s_waitcnt vmcnt(12)" ::: "memory");
            __builtin_amdgcn_s_barrier();
            __builtin_amdgcn_sched_barrier(0);

            const char* rb = smem + (kc & 3) * 8192;

            bf16x8 a[2];
            #pragma unroll
            for (int ks = 0; ks < 2; ++ks) {
                int c0 = ks * 8 + g * 2;
                float4 fa = *(const float4*)(rb + ra * 256 + ((c0       ^ rsw) << 4));
                float4 fb = *(const float4*)(rb + ra * 256 + (((c0 + 1) ^ rsw) << 4));
                a[ks] = cvt8r(fa, fb);
            }

            #pragma unroll
            for (int j = 0; j < 3; ++j) {
                #pragma unroll
                for (int ks = 0; ks < 2; ++ks) {
                    size_t fragofs = ((size_t)(j * 32 + kc * 2 + ks) * 64 + ln) * 8;
                    bf16x8 b = *(const bf16x8*)(wbase + fragofs);
                    acc[j] = __builtin_amdgcn_mfma_f32_16x16x32_bf16(a[ks], b, acc[j], 0, 0, 0);
                }
            }

            if (kc < 13) STAGE((kc + 3) & 3, kc + 3);
        }
#undef STAGE

        __syncthreads();

        float* tile = (float*)smem;
        #pragma unroll
        for (int j = 0; j < 3; ++j)
            #pragma unroll
            for (int i = 0; i < 4; ++i)
                tile[(ms * 16 + g * 4 + i) * 201 + nh * 48 + j * 16 + lr] = acc[j][i];
        __syncthreads();

        for (int uu = tid; uu < 768; uu += 512) {
            const int ln2 = uu & 63;
            const int lr2 = ln2 & 15;
            const int g2  = ln2 >> 4;
            if (uu < 512) {
                const int isK = uu >> 8;
                const int rem = uu & 255;
                const int u   = rem >> 7;
                const int ks  = (rem >> 6) & 1;
                const float* src = tile + (u * 16 + lr2) * 201 + isK * 64 + ks * 32 + g2 * 8;
                float4 f0 = *(const float4*)src;
                float4 f1 = *(const float4*)(src + 4);
                bf16x8 val = cvt8r(f0, f1);
                u16* dst = (isK ? kP : qP)
                         + ((size_t)(((m0 >> 4) + u) * 2 + ks) * 64 + ln2) * 8;
                *(bf16x8*)dst = val;
            } else {
                const int rem = uu - 512;
                const int jf  = rem >> 6;
                union { u16 h[8]; bf16x8 v; } ua;
                #pragma unroll
                for (int e = 0; e < 8; ++e)
                    ua.h[e] = f2bf(tile[(g2 * 8 + e) * 201 + 128 + jf * 16 + lr2]);
                u16* dst = vP + ((size_t)((m0 >> 5) * 4 + jf) * 64 + ln2) * 8;
                *(bf16x8*)dst = ua.v;
            }
        }
    }

    // ================= grid barrier (R16-proven pattern) ==================
    __syncthreads();
    if (tid == 0) {
        __threadfence();                               // publish qP/kP/vP
        atomicAdd(bar, 1u);
        while (__hip_atomic_load(bar, __ATOMIC_RELAXED, __HIP_MEMORY_SCOPE_AGENT) < GRID)
            __builtin_amdgcn_s_sleep(2);
        __threadfence();                               // acquire others' writes
    }
    __syncthreads();

    // ================= phase 2: attention (R27 body), 2 tiles/block =======
    const int seg = w;                                 // 0..7

    #pragma unroll 1
    for (int t2 = 0; t2 < 2; ++t2) {
        const int tix = (t2 == 0) ? blockIdx.x : (511 - blockIdx.x);
        const int b   = tix & 3;
        const int qt  = 127 - (tix >> 2);
        const int q0  = qt * 16;

        const int nch = (qt >> 2) + 1;
        const int L   = (nch + NSEG - 1) >> 3;
        const int c0  = seg * L;
        const int c1  = min(nch, c0 + L);

        f32x4 oacc[4] = {};
        float mrow[4], lrow[4];
        #pragma unroll
        for (int i = 0; i < 4; ++i) { mrow[i] = -1e30f; lrow[i] = 0.f; }

        if (c0 < c1) {
            bf16x8 aq[2];
            #pragma unroll
            for (int ks = 0; ks < 2; ++ks)
                aq[ks] = *(const bf16x8*)(qP + ((size_t)((b * 128 + qt) * 2 + ks) * 64 + ln) * 8);

            u16* myps = (u16*)shm + seg * 1152;

            for (int jc = c0; jc < c1; ++jc) {
                const int kv0 = jc << 6;

                bf16x8 bk[8];
                #pragma unroll
                for (int jf = 0; jf < 4; ++jf)
                    #pragma unroll
                    for (int ks = 0; ks < 2; ++ks)
                        bk[jf * 2 + ks] = *(const bf16x8*)(kP +
                            ((size_t)((b * 128 + (kv0 >> 4) + jf) * 2 + ks) * 64 + ln) * 8);

                f32x4 sacc[4] = {};
                #pragma unroll
                for (int jf = 0; jf < 4; ++jf)
                    #pragma unroll
                    for (int ks = 0; ks < 2; ++ks)
                        sacc[jf] = __builtin_amdgcn_mfma_f32_16x16x32_bf16(aq[ks], bk[jf * 2 + ks], sacc[jf], 0, 0, 0);

                bf16x8 bv[8];
                #pragma unroll
                for (int ks2 = 0; ks2 < 2; ++ks2)
                    #pragma unroll
                    for (int jf = 0; jf < 4; ++jf)
                        bv[jf * 2 + ks2] = *(const bf16x8*)(vP +
                            ((size_t)((b * 64 + (kv0 >> 5) + ks2) * 4 + jf) * 64 + ln) * 8);

                const bool full = (kv0 + 63 <= q0);
                #pragma unroll
                for (int jf = 0; jf < 4; ++jf) {
                    int col = kv0 + jf * 16 + lr;
                    #pragma unroll
                    for (int i = 0; i < 4; ++i) {
                        int row = q0 + g * 4 + i;
                        float val = sacc[jf][i] * 0.03125f;
                        sacc[jf][i] = (full || col <= row) ? val : -1e30f;
                    }
                }

                float pnew[4][4];
                #pragma unroll
                for (int i = 0; i < 4; ++i) {
                    float mx = fmaxf(fmaxf(sacc[0][i], sacc[1][i]), fmaxf(sacc[2][i], sacc[3][i]));
                    mx = fmaxf(mx, __shfl_xor(mx, 1));
                    mx = fmaxf(mx, __shfl_xor(mx, 2));
                    mx = fmaxf(mx, __shfl_xor(mx, 4));
                    mx = fmaxf(mx, __shfl_xor(mx, 8));
                    float mnew = fmaxf(mrow[i], mx);
                    float corr = __expf(mrow[i] - mnew);
                    float rs = 0.f;
                    #pragma unroll
                    for (int jf = 0; jf < 4; ++jf) {
                        float p = __expf(sacc[jf][i] - mnew);
                        pnew[jf][i] = p;
                        rs += p;
                    }
                    rs += __shfl_xor(rs, 1);
                    rs += __shfl_xor(rs, 2);
                    rs += __shfl_xor(rs, 4);
                    rs += __shfl_xor(rs, 8);
                    lrow[i] = lrow[i] * corr + rs;
                    mrow[i] = mnew;
                    #pragma unroll
                    for (int jf = 0; jf < 4; ++jf) oacc[jf][i] *= corr;
                }

                #pragma unroll
                for (int jf = 0; jf < 4; ++jf)
                    #pragma unroll
                    for (int i = 0; i < 4; ++i)
                        myps[(g * 4 + i) * 72 + jf * 16 + lr] = f2bf(pnew[jf][i]);

                #pragma unroll
                for (int ks2 = 0; ks2 < 2; ++ks2) {
                    bf16x8 ap = *(const bf16x8*)(myps + lr * 72 + ks2 * 32 + lk);
                    #pragma unroll
                    for (int jf = 0; jf < 4; ++jf)
                        oacc[jf] = __builtin_amdgcn_mfma_f32_16x16x32_bf16(ap, bv[jf * 2 + ks2], oacc[jf], 0, 0, 0);
                }
            }
        }

        __syncthreads();   // ps region dead; alias part/mlp onto it

        float* part = (float*)shm;                 // [8][16][66]
        float* mlp  = part + 8 * 16 * 66;          // [8][16][2]

        if (c0 >= c1) {
            if (lr == 0)
                #pragma unroll
                for (int i = 0; i < 4; ++i) {
                    mlp[(seg * 16 + g * 4 + i) * 2]     = -1e30f;
                    mlp[(seg * 16 + g * 4 + i) * 2 + 1] = 0.f;
                }
        } else {
            #pragma unroll
            for (int jf = 0; jf < 4; ++jf)
                #pragma unroll
                for (int i = 0; i < 4; ++i)
                    part[(seg * 16 + g * 4 + i) * 66 + jf * 16 + lr] = oacc[jf][i];
            if (lr == 0)
                #pragma unroll
                for (int i = 0; i < 4; ++i) {
                    mlp[(seg * 16 + g * 4 + i) * 2]     = mrow[i];
                    mlp[(seg * 16 + g * 4 + i) * 2 + 1] = lrow[i];
                }
        }

        __syncthreads();

        if (tid < 256) {
            const int row = tid >> 4;
            const int p   = tid & 15;

            float m2[NSEG], l2[NSEG];
            #pragma unroll
            for (int s = 0; s < NSEG; ++s) {
                m2[s] = mlp[(s * 16 + row) * 2];
                l2[s] = mlp[(s * 16 + row) * 2 + 1];
            }
            float M = m2[0];
            #pragma unroll
            for (int s = 1; s < NSEG; ++s) M = fmaxf(M, m2[s]);

            float a0 = 0.f, a1 = 0.f, a2 = 0.f, a3 = 0.f, Lsum = 0.f;
            #pragma unroll
            for (int s = 0; s < NSEG; ++s) {
                if (l2[s] != 0.f) {
                    float wgt = __expf(m2[s] - M);
                    Lsum += l2[s] * wgt;
                    const float* pp = part + (s * 16 + row) * 66 + p * 4;
                    a0 += wgt * pp[0];
                    a1 += wgt * pp[1];
                    a2 += wgt * pp[2];
                    a3 += wgt * pp[3];
                }
            }
            float inv = 1.f / Lsum;
            float4 r; r.x = a0 * inv; r.y = a1 * inv; r.z = a2 * inv; r.w = a3 * inv;
            *(float4*)(out + ((size_t)b * T_ + qt * 16 + row) * H_ + p * 4) = r;
        }

        __syncthreads();   // merge reads done before next tile reuses ps region
    }
}

extern "C" void kernel_launch(void* const* d_in, const int* in_sizes, int n_in,
                              void* d_out, int out_size, void* d_ws, size_t ws_size,
                              hipStream_t stream) {
    const float* x  = (const float*)d_in[0];
    const float* wq = (const float*)d_in[1];
    const float* wk = (const float*)d_in[2];
    const float* wv = (const float*)d_in[3];

    unsigned* bar = (unsigned*)d_ws;                 // barrier counter (256B pad)
    u16* qPws = (u16*)((char*)d_ws + 256);           // 1 MB
    u16* kPws = qPws + (size_t)B_ * T_ * H_;         // 1 MB
    u16* vPws = kPws + (size_t)B_ * T_ * H_;         // 1 MB
    u16* wPws = vPws + (size_t)B_ * T_ * H_;         // 384 KB

    wpack<<<96, 256, 0, stream>>>(wq, wk, wv, wPws, bar);
    fused<<<GRID, 512, 0, stream>>>(x, wPws, qPws, kPws, vPws, (float*)d_out, bar);
}

// Round 30
// 37.843 us; speedup vs baseline: 1.5323x; 1.5323x over previous
//
#include <hip/hip_runtime.h>
#include <hip/hip_bf16.h>

typedef unsigned short u16;
typedef __attribute__((ext_vector_type(8))) __bf16 bf16x8;
typedef __attribute__((ext_vector_type(4))) float f32x4;

#define B_ 4
#define T_ 2048
#define C_ 1024
#define H_ 64
#define NSEG 8

__device__ __forceinline__ u16 f2bf(float f) {
    union { __hip_bfloat16 h; u16 u; } cv;
    cv.h = __float2bfloat16(f);
    return cv.u;
}

__device__ __forceinline__ bf16x8 cvt8r(float4 f0, float4 f1) {
    union { u16 h[8]; bf16x8 v; } ua;
    ua.h[0] = f2bf(f0.x); ua.h[1] = f2bf(f0.y);
    ua.h[2] = f2bf(f0.z); ua.h[3] = f2bf(f0.w);
    ua.h[4] = f2bf(f1.x); ua.h[5] = f2bf(f1.y);
    ua.h[6] = f2bf(f1.z); ua.h[7] = f2bf(f1.w);
    return ua.v;
}

// async global -> LDS, 16B per lane; LDS dest = uniform base + lane*16
__device__ __forceinline__ void gll16(const void* g, void* l) {
    __builtin_amdgcn_global_load_lds(
        (const __attribute__((address_space(1))) void*)g,
        (__attribute__((address_space(3))) void*)l, 16, 0, 0);
}

// ---------------- Kernel 0: W fp32 -> FRAGMENT-PACKED bf16 ----------------
__global__ __launch_bounds__(256) void wpack(
    const float* __restrict__ wq, const float* __restrict__ wk,
    const float* __restrict__ wv, u16* __restrict__ wP)
{
    int u    = blockIdx.x * 256 + threadIdx.x;   // 0..24575
    int ln   = u & 63;
    int frag = u >> 6;                           // 0..383
    int ksg  = frag & 31;
    int j16  = frag >> 5;                        // 0..11
    int n    = j16 * 16 + (ln & 15);
    int kb   = ksg * 32 + (ln >> 4) * 8;
    const float* src = (n < 64) ? (wq + (size_t)n * C_)
                     : (n < 128) ? (wk + (size_t)(n - 64) * C_)
                                 : (wv + (size_t)(n - 128) * C_);
    float4 f0 = *(const float4*)(src + kb);
    float4 f1 = *(const float4*)(src + kb + 4);
    *(bf16x8*)(wP + (size_t)u * 8) = cvt8r(f0, f1);
}

// ---------------- Kernel 1: QKV projection, counted-vmcnt pipeline --------
// 256 blocks x 512 thr. 4-buffer x-staging, 3-deep prefetch; ONE raw
// s_barrier per chunk with EXACT counted vmcnt (B-loads share the counter:
// steady-state wait is vmcnt(14)).
__global__ __launch_bounds__(512) void qkv(
    const float* __restrict__ x, const u16* __restrict__ wP,
    u16* __restrict__ qP, u16* __restrict__ kP, u16* __restrict__ vP)
{
    __shared__ __align__(16) char smem[32768];   // 4 x 8KB staging | epilogue tile

    const int tid = threadIdx.x;
    const int ln  = tid & 63;
    const int w   = tid >> 6;                    // 0..7
    const int m0  = blockIdx.x * 32;

    const int lr = ln & 15;
    const int g  = ln >> 4;
    const int ms = w >> 2;
    const int nh = w & 3;

    f32x4 acc[3] = {};

    const int xrow = w * 4 + (ln >> 4);
    const int xc   = (ln & 15) ^ (xrow & 7);

#define STAGE(BUF, KC)                                                     \
    gll16(x + (size_t)(m0 + xrow) * C_ + (KC) * 64 + xc * 4,               \
          smem + (BUF) * 8192 + w * 1024)

    // prologue: 3-deep prefetch (1 gll16/wave each)
    STAGE(0, 0);
    STAGE(1, 1);
    STAGE(2, 2);

    const int ra  = ms * 16 + lr;
    const int rsw = ra & 7;
    const u16* wbase = wP + (size_t)(nh * 3) * 32 * 64 * 8;

    #pragma unroll
    for (int kc = 0; kc < 16; ++kc) {
        // exact post-stage(kc) issue counts (loop fully unrolled -> immediates)
        if (kc == 0)       asm volatile("s_waitcnt vmcnt(2)"  ::: "memory");
        else if (kc == 1)  asm volatile("s_waitcnt vmcnt(8)"  ::: "memory");
        else if (kc <= 13) asm volatile("s_waitcnt vmcnt(14)" ::: "memory");
        else if (kc == 14) asm volatile("s_waitcnt vmcnt(13)" ::: "memory");
        else               asm volatile("s_waitcnt vmcnt(12)" ::: "memory");
        __builtin_amdgcn_s_barrier();            // all waves: buf(kc) staged
        __builtin_amdgcn_sched_barrier(0);       // pin ds_reads behind the wait

        const char* rb = smem + (kc & 3) * 8192;

        bf16x8 a[2];
        #pragma unroll
        for (int ks = 0; ks < 2; ++ks) {
            int c0 = ks * 8 + g * 2;
            float4 fa = *(const float4*)(rb + ra * 256 + ((c0       ^ rsw) << 4));
            float4 fb = *(const float4*)(rb + ra * 256 + (((c0 + 1) ^ rsw) << 4));
            a[ks] = cvt8r(fa, fb);
        }

        #pragma unroll
        for (int j = 0; j < 3; ++j) {
            #pragma unroll
            for (int ks = 0; ks < 2; ++ks) {
                size_t fragofs = ((size_t)(j * 32 + kc * 2 + ks) * 64 + ln) * 8;
                bf16x8 b = *(const bf16x8*)(wbase + fragofs);
                acc[j] = __builtin_amdgcn_mfma_f32_16x16x32_bf16(a[ks], b, acc[j], 0, 0, 0);
            }
        }

        if (kc < 13) STAGE((kc + 3) & 3, kc + 3);
    }
#undef STAGE

    __syncthreads();

    // epilogue: acc -> LDS f32 tile [32][201] -> packed coalesced writes
    float* tile = (float*)smem;
    #pragma unroll
    for (int j = 0; j < 3; ++j)
        #pragma unroll
        for (int i = 0; i < 4; ++i)
            tile[(ms * 16 + g * 4 + i) * 201 + nh * 48 + j * 16 + lr] = acc[j][i];
    __syncthreads();

    for (int uu = tid; uu < 768; uu += 512) {
        const int ln2 = uu & 63;
        const int lr2 = ln2 & 15;
        const int g2  = ln2 >> 4;
        if (uu < 512) {
            const int isK = uu >> 8;
            const int rem = uu & 255;
            const int u   = rem >> 7;
            const int ks  = (rem >> 6) & 1;
            const float* src = tile + (u * 16 + lr2) * 201 + isK * 64 + ks * 32 + g2 * 8;
            float4 f0 = *(const float4*)src;
            float4 f1 = *(const float4*)(src + 4);
            bf16x8 val = cvt8r(f0, f1);
            u16* dst = (isK ? kP : qP)
                     + ((size_t)(((m0 >> 4) + u) * 2 + ks) * 64 + ln2) * 8;
            *(bf16x8*)dst = val;
        } else {
            const int rem = uu - 512;
            const int jf  = rem >> 6;
            union { u16 h[8]; bf16x8 v; } ua;
            #pragma unroll
            for (int e = 0; e < 8; ++e)
                ua.h[e] = f2bf(tile[(g2 * 8 + e) * 201 + 128 + jf * 16 + lr2]);
            u16* dst = vP + ((size_t)((m0 >> 5) * 4 + jf) * 64 + ln2) * 8;
            *(bf16x8*)dst = ua.v;
        }
    }
}

// ---------------- Kernel 2: attention, 8 segments in-block, LDS union ----
__global__ __launch_bounds__(512) void attn(
    const u16* __restrict__ qP, const u16* __restrict__ kP,
    const u16* __restrict__ vP, float* __restrict__ out)
{
    __shared__ __align__(16) char shm[34816];  // ps aliases part/mlp

    const int tid  = threadIdx.x;
    const int lane = tid & 63;
    const int seg  = tid >> 6;             // 0..7
    const int tix  = blockIdx.x;
    const int b    = tix & 3;
    const int qt   = 127 - (tix >> 2);
    const int q0   = qt * 16;

    const int lr = lane & 15;
    const int g  = lane >> 4;
    const int lk = g * 8;

    const int nch = (qt >> 2) + 1;
    const int L   = (nch + NSEG - 1) >> 3;
    const int c0  = seg * L;
    const int c1  = min(nch, c0 + L);

    f32x4 oacc[4] = {};
    float mrow[4], lrow[4];
    #pragma unroll
    for (int i = 0; i < 4; ++i) { mrow[i] = -1e30f; lrow[i] = 0.f; }

    if (c0 < c1) {
        bf16x8 aq[2];
        #pragma unroll
        for (int ks = 0; ks < 2; ++ks)
            aq[ks] = *(const bf16x8*)(qP + ((size_t)((b * 128 + qt) * 2 + ks) * 64 + lane) * 8);

        u16* myps = (u16*)shm + seg * 1152;

        for (int jc = c0; jc < c1; ++jc) {
            const int kv0 = jc << 6;

            bf16x8 bk[8];
            #pragma unroll
            for (int jf = 0; jf < 4; ++jf)
                #pragma unroll
                for (int ks = 0; ks < 2; ++ks)
                    bk[jf * 2 + ks] = *(const bf16x8*)(kP +
                        ((size_t)((b * 128 + (kv0 >> 4) + jf) * 2 + ks) * 64 + lane) * 8);

            f32x4 sacc[4] = {};
            #pragma unroll
            for (int jf = 0; jf < 4; ++jf)
                #pragma unroll
                for (int ks = 0; ks < 2; ++ks)
                    sacc[jf] = __builtin_amdgcn_mfma_f32_16x16x32_bf16(aq[ks], bk[jf * 2 + ks], sacc[jf], 0, 0, 0);

            bf16x8 bv[8];
            #pragma unroll
            for (int ks2 = 0; ks2 < 2; ++ks2)
                #pragma unroll
                for (int jf = 0; jf < 4; ++jf)
                    bv[jf * 2 + ks2] = *(const bf16x8*)(vP +
                        ((size_t)((b * 64 + (kv0 >> 5) + ks2) * 4 + jf) * 64 + lane) * 8);

            const bool full = (kv0 + 63 <= q0);
            #pragma unroll
            for (int jf = 0; jf < 4; ++jf) {
                int col = kv0 + jf * 16 + lr;
                #pragma unroll
                for (int i = 0; i < 4; ++i) {
                    int row = q0 + g * 4 + i;
                    float val = sacc[jf][i] * 0.03125f;
                    sacc[jf][i] = (full || col <= row) ? val : -1e30f;
                }
            }

            float pnew[4][4];
            #pragma unroll
            for (int i = 0; i < 4; ++i) {
                float mx = fmaxf(fmaxf(sacc[0][i], sacc[1][i]), fmaxf(sacc[2][i], sacc[3][i]));
                mx = fmaxf(mx, __shfl_xor(mx, 1));
                mx = fmaxf(mx, __shfl_xor(mx, 2));
                mx = fmaxf(mx, __shfl_xor(mx, 4));
                mx = fmaxf(mx, __shfl_xor(mx, 8));
                float mnew = fmaxf(mrow[i], mx);
                float corr = __expf(mrow[i] - mnew);
                float rs = 0.f;
                #pragma unroll
                for (int jf = 0; jf < 4; ++jf) {
                    float p = __expf(sacc[jf][i] - mnew);
                    pnew[jf][i] = p;
                    rs += p;
                }
                rs += __shfl_xor(rs, 1);
                rs += __shfl_xor(rs, 2);
                rs += __shfl_xor(rs, 4);
                rs += __shfl_xor(rs, 8);
                lrow[i] = lrow[i] * corr + rs;
                mrow[i] = mnew;
                #pragma unroll
                for (int jf = 0; jf < 4; ++jf) oacc[jf][i] *= corr;
            }

            #pragma unroll
            for (int jf = 0; jf < 4; ++jf)
                #pragma unroll
                for (int i = 0; i < 4; ++i)
                    myps[(g * 4 + i) * 72 + jf * 16 + lr] = f2bf(pnew[jf][i]);

            #pragma unroll
            for (int ks2 = 0; ks2 < 2; ++ks2) {
                bf16x8 ap = *(const bf16x8*)(myps + lr * 72 + ks2 * 32 + lk);
                #pragma unroll
                for (int jf = 0; jf < 4; ++jf)
                    oacc[jf] = __builtin_amdgcn_mfma_f32_16x16x32_bf16(ap, bv[jf * 2 + ks2], oacc[jf], 0, 0, 0);
            }
        }
    }

    __syncthreads();   // ps region dead; alias part/mlp onto it

    float* part = (float*)shm;                 // [8][16][66]
    float* mlp  = part + 8 * 16 * 66;          // [8][16][2]

    if (c0 >= c1) {
        if (lr == 0)
            #pragma unroll
            for (int i = 0; i < 4; ++i) {
                mlp[(seg * 16 + g * 4 + i) * 2]     = -1e30f;
                mlp[(seg * 16 + g * 4 + i) * 2 + 1] = 0.f;
            }
    } else {
        #pragma unroll
        for (int jf = 0; jf < 4; ++jf)
            #pragma unroll
            for (int i = 0; i < 4; ++i)
                part[(seg * 16 + g * 4 + i) * 66 + jf * 16 + lr] = oacc[jf][i];
        if (lr == 0)
            #pragma unroll
            for (int i = 0; i < 4; ++i) {
                mlp[(seg * 16 + g * 4 + i) * 2]     = mrow[i];
                mlp[(seg * 16 + g * 4 + i) * 2 + 1] = lrow[i];
            }
    }

    __syncthreads();

    if (tid < 256) {
        const int row = tid >> 4;
        const int p   = tid & 15;

        float m2[NSEG], l2[NSEG];
        #pragma unroll
        for (int s = 0; s < NSEG; ++s) {
            m2[s] = mlp[(s * 16 + row) * 2];
            l2[s] = mlp[(s * 16 + row) * 2 + 1];
        }
        float M = m2[0];
        #pragma unroll
        for (int s = 1; s < NSEG; ++s) M = fmaxf(M, m2[s]);

        float a0 = 0.f, a1 = 0.f, a2 = 0.f, a3 = 0.f, Lsum = 0.f;
        #pragma unroll
        for (int s = 0; s < NSEG; ++s) {
            if (l2[s] != 0.f) {
                float wgt = __expf(m2[s] - M);
                Lsum += l2[s] * wgt;
                const float* pp = part + (s * 16 + row) * 66 + p * 4;
                a0 += wgt * pp[0];
                a1 += wgt * pp[1];
                a2 += wgt * pp[2];
                a3 += wgt * pp[3];
            }
        }
        float inv = 1.f / Lsum;
        float4 r; r.x = a0 * inv; r.y = a1 * inv; r.z = a2 * inv; r.w = a3 * inv;
        *(float4*)(out + ((size_t)b * T_ + qt * 16 + row) * H_ + p * 4) = r;
    }
}

extern "C" void kernel_launch(void* const* d_in, const int* in_sizes, int n_in,
                              void* d_out, int out_size, void* d_ws, size_t ws_size,
                              hipStream_t stream) {
    const float* x  = (const float*)d_in[0];
    const float* wq = (const float*)d_in[1];
    const float* wk = (const float*)d_in[2];
    const float* wv = (const float*)d_in[3];

    u16* qPws = (u16*)d_ws;                          // 1 MB
    u16* kPws = qPws + (size_t)B_ * T_ * H_;         // 1 MB
    u16* vPws = kPws + (size_t)B_ * T_ * H_;         // 1 MB
    u16* wPws = vPws + (size_t)B_ * T_ * H_;         // 384 KB

    wpack<<<96, 256, 0, stream>>>(wq, wk, wv, wPws);
    qkv<<<256, 512, 0, stream>>>(x, wPws, qPws, kPws, vPws);
    attn<<<512, 512, 0, stream>>>(qPws, kPws, vPws, (float*)d_out);
}